// Round 10
// baseline (594.955 us; speedup 1.0000x reference)
//
#include <hip/hip_runtime.h>

typedef _Float16 half8 __attribute__((ext_vector_type(8)));
typedef _Float16 half4v __attribute__((ext_vector_type(4)));
typedef float f32x4 __attribute__((ext_vector_type(4)));

__device__ __forceinline__ void gld_lds16(const void* g, void* l) {
  __builtin_amdgcn_global_load_lds((const __attribute__((address_space(1))) void*)g,
                                   (__attribute__((address_space(3))) void*)l, 16, 0, 0);
}

// ---------------- fp32 -> f16 convert (vectorized) ----------------
__global__ void cvt_f32_f16(const float* __restrict__ src, _Float16* __restrict__ dst, int n4) {
  int i = blockIdx.x * 256 + threadIdx.x;
  if (i < n4) {
    float4 v = ((const float4*)src)[i];
    half4v h;
    h.x = (_Float16)v.x; h.y = (_Float16)v.y; h.z = (_Float16)v.z; h.w = (_Float16)v.w;
    ((half4v*)dst)[i] = h;
  }
}

// ---------------- mask tile flags: flag=1 iff no zeros in 128x64 tile ----------------
__global__ void mask_flags_k(const int* __restrict__ mask, unsigned char* __restrict__ flags) {
  int qt = blockIdx.x, kt = blockIdx.y; // 16 x 32
  __shared__ int allv;
  if (threadIdx.x == 0) allv = 1;
  __syncthreads();
  int ok = 1;
  for (int idx = threadIdx.x; idx < 128 * 64; idx += 256) {
    int qr = qt * 128 + (idx >> 6);
    int kc = kt * 64 + (idx & 63);
    ok &= (mask[(size_t)qr * 2048 + kc] != 0);
  }
  if (!ok) atomicAnd(&allv, 0);
  __syncthreads();
  if (threadIdx.x == 0) flags[qt * 32 + kt] = (unsigned char)allv;
}

// ---------------- GEMM: y[M=8192,N=1024] = A[M,1024] @ B[N,1024]^T + bias, * oscale ----------
// LAYOUT 0: f16 heads [b,h,s,d]   LAYOUT 1: f16 V^T [b,h,d,s]   LAYOUT 2: fp32 [row,col]
// XCD-aware remap (T1): linear wg -> xcd = wg&7 owns an 8x8 (m,n) tile block so A-panels
// and B-panels are shared within one XCD's L2 (working set 4MB). Bijective for 512 blocks.
template <int LAYOUT>
__global__ __launch_bounds__(256, 2) void gemm_k(const _Float16* __restrict__ A,
                                                 const _Float16* __restrict__ B,
                                                 const float* __restrict__ bias,
                                                 void* __restrict__ dst, float oscale) {
  __shared__ _Float16 Alds[128][32];
  __shared__ _Float16 Blds[128][32];
  int tid = threadIdx.x, w = tid >> 6, l = tid & 63;
  int lm = l & 15, lg = l >> 4;
  int wm = w >> 1, wn = w & 1;
  int wg = blockIdx.y * 8 + blockIdx.x;  // linear id, x fastest
  int xcd = wg & 7, j = wg >> 3;
  int m0 = (xcd * 8 + (j >> 3)) * 128, n0 = (j & 7) * 128;
  f32x4 acc[4][4] = {};
  for (int k0 = 0; k0 < 1024; k0 += 32) {
#pragma unroll
    for (int c = 0; c < 2; ++c) {
      int o = w * 2048 + c * 1024 + l * 16;  // byte offset within 8KB tile
      int row = o >> 6;
      int kb = (o & 63) >> 1;  // f16 element offset within row
      gld_lds16(A + (size_t)(m0 + row) * 1024 + k0 + kb, (char*)&Alds[0][0] + w * 2048 + c * 1024);
      gld_lds16(B + (size_t)(n0 + row) * 1024 + k0 + kb, (char*)&Blds[0][0] + w * 2048 + c * 1024);
    }
    __syncthreads();
    half8 af[4], bf[4];
#pragma unroll
    for (int m = 0; m < 4; ++m) af[m] = *(const half8*)&Alds[wm * 64 + m * 16 + lm][lg * 8];
#pragma unroll
    for (int n = 0; n < 4; ++n) bf[n] = *(const half8*)&Blds[wn * 64 + n * 16 + lm][lg * 8];
#pragma unroll
    for (int m = 0; m < 4; ++m)
#pragma unroll
      for (int n = 0; n < 4; ++n)
        acc[m][n] = __builtin_amdgcn_mfma_f32_16x16x32_f16(af[m], bf[n], acc[m][n], 0, 0, 0);
    __syncthreads();
  }
  float bs[4];
#pragma unroll
  for (int n = 0; n < 4; ++n) bs[n] = bias[n0 + wn * 64 + n * 16 + lm];
#pragma unroll
  for (int m = 0; m < 4; ++m) {
#pragma unroll
    for (int n = 0; n < 4; ++n) {
      int colg = n0 + wn * 64 + n * 16 + lm;
#pragma unroll
      for (int j2 = 0; j2 < 4; ++j2) {
        int rowg = m0 + wm * 64 + m * 16 + lg * 4 + j2;
        float v = (acc[m][n][j2] + bs[n]) * oscale;
        if constexpr (LAYOUT == 0) {
          int b = rowg >> 11, s = rowg & 2047, h = colg >> 6, d = colg & 63;
          ((_Float16*)dst)[((size_t)(b * 16 + h) * 2048 + s) * 64 + d] = (_Float16)v;
        } else if constexpr (LAYOUT == 1) {
          int b = rowg >> 11, s = rowg & 2047, h = colg >> 6, d = colg & 63;
          ((_Float16*)dst)[((size_t)(b * 16 + h) * 64 + d) * 2048 + s] = (_Float16)v;
        } else {
          ((float*)dst)[(size_t)rowg * 1024 + colg] = v;
        }
      }
    }
  }
}

// ---------------- flash attention ----------------
// ROUND 10: 1-wave blocks. grid (64 bh, 64 q32) = 4096 blocks = exactly 16/CU, no tail.
// __launch_bounds__(64,4) -> VGPR cap 128 (live ~100 fits: round 5/6 lesson, cap must
// exceed live set). Occupancy 12 -> 16 waves/CU of fully independent waves.
//  - K(t+1) prefetch issued AFTER this tile's V loads: PV's vmcnt wait for V leaves
//    K(t+1) in flight (round 8's failure was prefetch BEFORE V); K latency hides
//    under PV + loop.
//  - lrun kept as per-lane PARTIAL sums (valid under per-lane alpha rescale; the 4
//    lanes sharing a q-row hold identical mrun); single cross-lane reduce in epilogue.
//  - keeps: transposed PV (per-lane alpha/1/l), T13 defer-max, swapped QK^T,
//    log2-domain softmax, LDS-transpose epilogue, T1 XCD mapping (bh = x fastest).
__global__ __launch_bounds__(64, 4) void attn_k(const _Float16* __restrict__ Q,
                                                const _Float16* __restrict__ K,
                                                const _Float16* __restrict__ Vt,
                                                const unsigned char* __restrict__ flags,
                                                const int* __restrict__ mask,
                                                _Float16* __restrict__ out) {
  __shared__ __align__(16) char Plds[4096];  // 32 rows x 128B, XOR-swizzled
  int bh = blockIdx.x, q32 = blockIdx.y;
  int l = threadIdx.x & 63;
  int lm = l & 15, lg = l >> 4;
  const size_t hb = (size_t)bh * (2048 * 64);
  int q0 = q32 * 32;
  const _Float16* Kb = K + hb;
  const _Float16* Vb = Vt + hb;
  const unsigned char* fl = flags + (q32 >> 2) * 32;

  half8 qf[2][2];
#pragma unroll
  for (int m = 0; m < 2; ++m)
#pragma unroll
    for (int kk = 0; kk < 2; ++kk)
      qf[m][kk] = *(const half8*)&Q[hb + (size_t)(q0 + m * 16 + lm) * 64 + kk * 32 + lg * 8];

  f32x4 oaccT[2][4] = {};           // O^T: col=q=lm (per-lane row), row=d
  float mrun[2] = {-1e30f, -1e30f};
  float lrun[2] = {0.f, 0.f};       // per-lane PARTIAL row-sums (reduced in epilogue)

  // K fragments for tile 0
  half8 kf[4][2];
#pragma unroll
  for (int n = 0; n < 4; ++n)
#pragma unroll
    for (int kk = 0; kk < 2; ++kk)
      kf[n][kk] = *(const half8*)&Kb[(size_t)(n * 16 + lm) * 64 + kk * 32 + lg * 8];

  for (int t = 0; t < 32; ++t) {
    int flg = fl[t];
    f32x4 sT[2][4];
    f32x4 z = {0.f, 0.f, 0.f, 0.f};
    __builtin_amdgcn_s_setprio(1);
#pragma unroll
    for (int m = 0; m < 2; ++m)
#pragma unroll
      for (int n = 0; n < 4; ++n) {
        sT[m][n] = __builtin_amdgcn_mfma_f32_16x16x32_f16(kf[n][0], qf[m][0], z, 0, 0, 0);
        sT[m][n] = __builtin_amdgcn_mfma_f32_16x16x32_f16(kf[n][1], qf[m][1], sT[m][n], 0, 0, 0);
      }
    __builtin_amdgcn_s_setprio(0);
    // V for THIS tile: latency hides under softmax; oldest in vmcnt queue.
    half8 vf[4][2];
#pragma unroll
    for (int n = 0; n < 4; ++n)
#pragma unroll
      for (int kk = 0; kk < 2; ++kk)
        vf[n][kk] = *(const half8*)&Vb[(size_t)(n * 16 + lm) * 2048 + t * 64 + kk * 32 + lg * 8];
    // K for NEXT tile, issued AFTER V: PV's wait for V does not drain these.
    if (t < 31) {
#pragma unroll
      for (int n = 0; n < 4; ++n)
#pragma unroll
        for (int kk = 0; kk < 2; ++kk)
          kf[n][kk] = *(const half8*)&Kb[(size_t)((t + 1) * 64 + n * 16 + lm) * 64 + kk * 32 + lg * 8];
    }
    if (!flg) {  // slow path: per-element mask (not taken for all-ones mask)
#pragma unroll
      for (int m = 0; m < 2; ++m)
#pragma unroll
        for (int n = 0; n < 4; ++n)
#pragma unroll
          for (int j = 0; j < 4; ++j) {
            int qr = q0 + m * 16 + lm;
            int kc = t * 64 + n * 16 + lg * 4 + j;
            if (mask[(size_t)qr * 2048 + kc] == 0) sT[m][n][j] = -1e30f;
          }
    }
#pragma unroll
    for (int m = 0; m < 2; ++m) {
      float mx[4], ps[4];
#pragma unroll
      for (int n = 0; n < 4; ++n)
        mx[n] = fmaxf(fmaxf(sT[m][n][0], sT[m][n][1]), fmaxf(sT[m][n][2], sT[m][n][3]));
      float pmax = fmaxf(fmaxf(mx[0], mx[1]), fmaxf(mx[2], mx[3]));
      pmax = fmaxf(pmax, __shfl_xor(pmax, 16, 64));
      pmax = fmaxf(pmax, __shfl_xor(pmax, 32, 64));
      // T13 defer-max: only rescale when some row grew by > 8 (log2 domain)
      if (!__all(pmax - mrun[m] <= 8.f)) {
        float mnew = fmaxf(mrun[m], pmax);
        float alpha = exp2f(mrun[m] - mnew);   // per-lane scalar (col=q=lm)
#pragma unroll
        for (int n = 0; n < 4; ++n)
#pragma unroll
          for (int j = 0; j < 4; ++j) oaccT[m][n][j] *= alpha;
        lrun[m] *= alpha;
        mrun[m] = mnew;
      }
      int row = m * 16 + lm;
#pragma unroll
      for (int n = 0; n < 4; ++n) {
        half4v p4;
        float pp[4];
#pragma unroll
        for (int j = 0; j < 4; ++j) {
          pp[j] = exp2f(sT[m][n][j] - mrun[m]);  // log2-domain; bounded by 2^8
          p4[j] = (_Float16)pp[j];
        }
        ps[n] = (pp[0] + pp[1]) + (pp[2] + pp[3]);
        int byte = row * 128 + (((n * 32 + lg * 8)) ^ ((row & 7) << 4));
        *(half4v*)(&Plds[byte]) = p4;
      }
      lrun[m] += (ps[0] + ps[1]) + (ps[2] + ps[3]);  // per-lane partial, no shfl
    }
    // read P as fragments (B-operand of transposed PV; bit-identical read)
    half8 pa[2][2];
#pragma unroll
    for (int m = 0; m < 2; ++m)
#pragma unroll
      for (int ks = 0; ks < 2; ++ks) {
        int row = m * 16 + lm;
        int byte = row * 128 + ((ks * 64 + lg * 16) ^ ((row & 7) << 4));
        pa[m][ks] = *(const half8*)(&Plds[byte]);
      }
    __builtin_amdgcn_s_setprio(1);
#pragma unroll
    for (int n = 0; n < 4; ++n)
#pragma unroll
      for (int m = 0; m < 2; ++m) {
        // O^T = V^T * P^T : rows=d (vf), cols=q (pa)
        oaccT[m][n] = __builtin_amdgcn_mfma_f32_16x16x32_f16(vf[n][0], pa[m][0], oaccT[m][n], 0, 0, 0);
        oaccT[m][n] = __builtin_amdgcn_mfma_f32_16x16x32_f16(vf[n][1], pa[m][1], oaccT[m][n], 0, 0, 0);
      }
    __builtin_amdgcn_s_setprio(0);
  }
  // epilogue: reduce lrun partials across the 4 lanes sharing each q-row, normalize,
  // transpose O^T -> O through LDS, coalesced 16B stores
  int b = bh >> 4, h = bh & 15;
#pragma unroll
  for (int m = 0; m < 2; ++m) {
    float lsum = lrun[m];
    lsum += __shfl_xor(lsum, 16, 64);
    lsum += __shfl_xor(lsum, 32, 64);
    float rinv = 1.0f / lsum;
    int row = m * 16 + lm;       // q-local row this lane owns
#pragma unroll
    for (int n = 0; n < 4; ++n) {
      half4v p4;
#pragma unroll
      for (int j = 0; j < 4; ++j) p4[j] = (_Float16)(oaccT[m][n][j] * rinv);
      int byte = row * 128 + ((n * 32 + lg * 8) ^ ((row & 7) << 4));
      *(half4v*)(&Plds[byte]) = p4;
    }
  }
#pragma unroll
  for (int r = 0; r < 4; ++r) {
    int o = r * 1024 + l * 16;
    int row = o >> 7;            // 0..31
    int pb = o & 127;
    int d2 = pb ^ ((row & 7) << 4);  // logical byte-col (d*2)
    half8 v = *(const half8*)&Plds[row * 128 + pb];
    *(half8*)&out[((size_t)(b * 2048 + q0 + row)) * 1024 + h * 64 + (d2 >> 1)] = v;
  }
}

extern "C" void kernel_launch(void* const* d_in, const int* in_sizes, int n_in,
                              void* d_out, int out_size, void* d_ws, size_t ws_size,
                              hipStream_t stream) {
  const float* x = (const float*)d_in[0];
  const int* mask = (const int*)d_in[1];
  const float* Wq = (const float*)d_in[2];
  const float* bq = (const float*)d_in[3];
  const float* Wk = (const float*)d_in[4];
  const float* bk = (const float*)d_in[5];
  const float* Wv = (const float*)d_in[6];
  const float* bv = (const float*)d_in[7];
  const float* Wo = (const float*)d_in[8];
  const float* bo = (const float*)d_in[9];

  char* ws = (char*)d_ws;
  _Float16* xh = (_Float16*)(ws);                       // 16 MB, later reused as attn out
  _Float16* Wqh = (_Float16*)(ws + (16ull << 20));      // 2 MB
  _Float16* Wkh = (_Float16*)(ws + (18ull << 20));      // 2 MB
  _Float16* Wvh = (_Float16*)(ws + (20ull << 20));      // 2 MB
  _Float16* Woh = (_Float16*)(ws + (22ull << 20));      // 2 MB
  _Float16* Vt = (_Float16*)(ws + (24ull << 20));       // 16 MB
  unsigned char* flags = (unsigned char*)(ws + (40ull << 20));  // 512 B
  // Q and K scratch live inside d_out (32 MB fp32), fully overwritten by final GEMM
  _Float16* Qw = (_Float16*)d_out;
  _Float16* Kw = (_Float16*)((char*)d_out + (16ull << 20));
  _Float16* Ah = xh;  // attention output reuses x-f16 region

  const float QSCALE = 0.125f * 1.4426950408889634f;  // 1/sqrt(64) * log2(e)

  cvt_f32_f16<<<8192, 256, 0, stream>>>(x, xh, 2097152);
  cvt_f32_f16<<<1024, 256, 0, stream>>>(Wq, Wqh, 262144);
  cvt_f32_f16<<<1024, 256, 0, stream>>>(Wk, Wkh, 262144);
  cvt_f32_f16<<<1024, 256, 0, stream>>>(Wv, Wvh, 262144);
  cvt_f32_f16<<<1024, 256, 0, stream>>>(Wo, Woh, 262144);
  mask_flags_k<<<dim3(16, 32), 256, 0, stream>>>(mask, flags);
  gemm_k<0><<<dim3(8, 64), 256, 0, stream>>>(xh, Wqh, bq, Qw, QSCALE);
  gemm_k<0><<<dim3(8, 64), 256, 0, stream>>>(xh, Wkh, bk, Kw, 1.0f);
  gemm_k<1><<<dim3(8, 64), 256, 0, stream>>>(xh, Wvh, bv, Vt, 1.0f);
  attn_k<<<dim3(64, 64), 64, 0, stream>>>(Qw, Kw, Vt, flags, mask, Ah);
  gemm_k<2><<<dim3(8, 64), 256, 0, stream>>>(Ah, Woh, bo, d_out, 1.0f);
}

// Round 11
// 366.432 us; speedup vs baseline: 1.6236x; 1.6236x over previous
//
#include <hip/hip_runtime.h>

typedef _Float16 half8 __attribute__((ext_vector_type(8)));
typedef _Float16 half4v __attribute__((ext_vector_type(4)));
typedef float f32x4 __attribute__((ext_vector_type(4)));

__device__ __forceinline__ void gld_lds16(const void* g, void* l) {
  __builtin_amdgcn_global_load_lds((const __attribute__((address_space(1))) void*)g,
                                   (__attribute__((address_space(3))) void*)l, 16, 0, 0);
}

// ---------------- fp32 -> f16 convert (vectorized) ----------------
__global__ void cvt_f32_f16(const float* __restrict__ src, _Float16* __restrict__ dst, int n4) {
  int i = blockIdx.x * 256 + threadIdx.x;
  if (i < n4) {
    float4 v = ((const float4*)src)[i];
    half4v h;
    h.x = (_Float16)v.x; h.y = (_Float16)v.y; h.z = (_Float16)v.z; h.w = (_Float16)v.w;
    ((half4v*)dst)[i] = h;
  }
}

// ---------------- mask tile flags: flag=1 iff no zeros in 128x64 tile ----------------
__global__ void mask_flags_k(const int* __restrict__ mask, unsigned char* __restrict__ flags) {
  int qt = blockIdx.x, kt = blockIdx.y; // 16 x 32
  __shared__ int allv;
  if (threadIdx.x == 0) allv = 1;
  __syncthreads();
  int ok = 1;
  for (int idx = threadIdx.x; idx < 128 * 64; idx += 256) {
    int qr = qt * 128 + (idx >> 6);
    int kc = kt * 64 + (idx & 63);
    ok &= (mask[(size_t)qr * 2048 + kc] != 0);
  }
  if (!ok) atomicAnd(&allv, 0);
  __syncthreads();
  if (threadIdx.x == 0) flags[qt * 32 + kt] = (unsigned char)allv;
}

// ---------------- GEMM: y[M=8192,N=1024] = A[M,1024] @ B[N,1024]^T + bias, * oscale ----------
// LAYOUT 0: f16 heads [b,h,s,d]   LAYOUT 1: f16 V^T [b,h,d,s]   LAYOUT 2: fp32 [row,col]
// XCD-aware remap (T1): linear wg -> xcd = wg&7 owns an 8x8 (m,n) tile block so A-panels
// and B-panels are shared within one XCD's L2 (working set 4MB). Bijective for 512 blocks.
template <int LAYOUT>
__global__ __launch_bounds__(256, 2) void gemm_k(const _Float16* __restrict__ A,
                                                 const _Float16* __restrict__ B,
                                                 const float* __restrict__ bias,
                                                 void* __restrict__ dst, float oscale) {
  __shared__ _Float16 Alds[128][32];
  __shared__ _Float16 Blds[128][32];
  int tid = threadIdx.x, w = tid >> 6, l = tid & 63;
  int lm = l & 15, lg = l >> 4;
  int wm = w >> 1, wn = w & 1;
  int wg = blockIdx.y * 8 + blockIdx.x;  // linear id, x fastest
  int xcd = wg & 7, j = wg >> 3;
  int m0 = (xcd * 8 + (j >> 3)) * 128, n0 = (j & 7) * 128;
  f32x4 acc[4][4] = {};
  for (int k0 = 0; k0 < 1024; k0 += 32) {
#pragma unroll
    for (int c = 0; c < 2; ++c) {
      int o = w * 2048 + c * 1024 + l * 16;  // byte offset within 8KB tile
      int row = o >> 6;
      int kb = (o & 63) >> 1;  // f16 element offset within row
      gld_lds16(A + (size_t)(m0 + row) * 1024 + k0 + kb, (char*)&Alds[0][0] + w * 2048 + c * 1024);
      gld_lds16(B + (size_t)(n0 + row) * 1024 + k0 + kb, (char*)&Blds[0][0] + w * 2048 + c * 1024);
    }
    __syncthreads();
    half8 af[4], bf[4];
#pragma unroll
    for (int m = 0; m < 4; ++m) af[m] = *(const half8*)&Alds[wm * 64 + m * 16 + lm][lg * 8];
#pragma unroll
    for (int n = 0; n < 4; ++n) bf[n] = *(const half8*)&Blds[wn * 64 + n * 16 + lm][lg * 8];
#pragma unroll
    for (int m = 0; m < 4; ++m)
#pragma unroll
      for (int n = 0; n < 4; ++n)
        acc[m][n] = __builtin_amdgcn_mfma_f32_16x16x32_f16(af[m], bf[n], acc[m][n], 0, 0, 0);
    __syncthreads();
  }
  float bs[4];
#pragma unroll
  for (int n = 0; n < 4; ++n) bs[n] = bias[n0 + wn * 64 + n * 16 + lm];
#pragma unroll
  for (int m = 0; m < 4; ++m) {
#pragma unroll
    for (int n = 0; n < 4; ++n) {
      int colg = n0 + wn * 64 + n * 16 + lm;
#pragma unroll
      for (int j2 = 0; j2 < 4; ++j2) {
        int rowg = m0 + wm * 64 + m * 16 + lg * 4 + j2;
        float v = (acc[m][n][j2] + bs[n]) * oscale;
        if constexpr (LAYOUT == 0) {
          int b = rowg >> 11, s = rowg & 2047, h = colg >> 6, d = colg & 63;
          ((_Float16*)dst)[((size_t)(b * 16 + h) * 2048 + s) * 64 + d] = (_Float16)v;
        } else if constexpr (LAYOUT == 1) {
          int b = rowg >> 11, s = rowg & 2047, h = colg >> 6, d = colg & 63;
          ((_Float16*)dst)[((size_t)(b * 16 + h) * 64 + d) * 2048 + s] = (_Float16)v;
        } else {
          ((float*)dst)[(size_t)rowg * 1024 + colg] = v;
        }
      }
    }
  }
}

// ---------------- flash attention ----------------
// ROUND 11: R10 structure (1-wave blocks, grid (64 bh, 64 q32) = 4096 = 16/CU exactly,
// V-then-K(t+1) VMEM ordering, per-lane lrun partials, transposed PV, defer-max) but
// __launch_bounds__(64) with NO min-waves arg: every round that requested >=4 waves/EU
// (R5/R6/R10) got VGPR pinned to 64 + scratch spill (R10: 1.67GB spill traffic).
// Natural allocation (~100-130, cf. R2's 108) gives 512/VGPR ~= 4-5 waves/SIMD of
// hardware occupancy with zero spill - the config rounds 5-10 were aiming for.
__global__ __launch_bounds__(64) void attn_k(const _Float16* __restrict__ Q,
                                             const _Float16* __restrict__ K,
                                             const _Float16* __restrict__ Vt,
                                             const unsigned char* __restrict__ flags,
                                             const int* __restrict__ mask,
                                             _Float16* __restrict__ out) {
  __shared__ __align__(16) char Plds[4096];  // 32 rows x 128B, XOR-swizzled
  int bh = blockIdx.x, q32 = blockIdx.y;
  int l = threadIdx.x & 63;
  int lm = l & 15, lg = l >> 4;
  const size_t hb = (size_t)bh * (2048 * 64);
  int q0 = q32 * 32;
  const _Float16* Kb = K + hb;
  const _Float16* Vb = Vt + hb;
  const unsigned char* fl = flags + (q32 >> 2) * 32;

  half8 qf[2][2];
#pragma unroll
  for (int m = 0; m < 2; ++m)
#pragma unroll
    for (int kk = 0; kk < 2; ++kk)
      qf[m][kk] = *(const half8*)&Q[hb + (size_t)(q0 + m * 16 + lm) * 64 + kk * 32 + lg * 8];

  f32x4 oaccT[2][4] = {};           // O^T: col=q=lm (per-lane row), row=d
  float mrun[2] = {-1e30f, -1e30f};
  float lrun[2] = {0.f, 0.f};       // per-lane PARTIAL row-sums (reduced in epilogue)

  // K fragments for tile 0
  half8 kf[4][2];
#pragma unroll
  for (int n = 0; n < 4; ++n)
#pragma unroll
    for (int kk = 0; kk < 2; ++kk)
      kf[n][kk] = *(const half8*)&Kb[(size_t)(n * 16 + lm) * 64 + kk * 32 + lg * 8];

  for (int t = 0; t < 32; ++t) {
    int flg = fl[t];
    f32x4 sT[2][4];
    f32x4 z = {0.f, 0.f, 0.f, 0.f};
    __builtin_amdgcn_s_setprio(1);
#pragma unroll
    for (int m = 0; m < 2; ++m)
#pragma unroll
      for (int n = 0; n < 4; ++n) {
        sT[m][n] = __builtin_amdgcn_mfma_f32_16x16x32_f16(kf[n][0], qf[m][0], z, 0, 0, 0);
        sT[m][n] = __builtin_amdgcn_mfma_f32_16x16x32_f16(kf[n][1], qf[m][1], sT[m][n], 0, 0, 0);
      }
    __builtin_amdgcn_s_setprio(0);
    // V for THIS tile: latency hides under softmax; oldest in vmcnt queue.
    half8 vf[4][2];
#pragma unroll
    for (int n = 0; n < 4; ++n)
#pragma unroll
      for (int kk = 0; kk < 2; ++kk)
        vf[n][kk] = *(const half8*)&Vb[(size_t)(n * 16 + lm) * 2048 + t * 64 + kk * 32 + lg * 8];
    // K for NEXT tile, issued AFTER V: PV's wait for V does not drain these.
    if (t < 31) {
#pragma unroll
      for (int n = 0; n < 4; ++n)
#pragma unroll
        for (int kk = 0; kk < 2; ++kk)
          kf[n][kk] = *(const half8*)&Kb[(size_t)((t + 1) * 64 + n * 16 + lm) * 64 + kk * 32 + lg * 8];
    }
    if (!flg) {  // slow path: per-element mask (not taken for all-ones mask)
#pragma unroll
      for (int m = 0; m < 2; ++m)
#pragma unroll
        for (int n = 0; n < 4; ++n)
#pragma unroll
          for (int j = 0; j < 4; ++j) {
            int qr = q0 + m * 16 + lm;
            int kc = t * 64 + n * 16 + lg * 4 + j;
            if (mask[(size_t)qr * 2048 + kc] == 0) sT[m][n][j] = -1e30f;
          }
    }
#pragma unroll
    for (int m = 0; m < 2; ++m) {
      float mx[4], ps[4];
#pragma unroll
      for (int n = 0; n < 4; ++n)
        mx[n] = fmaxf(fmaxf(sT[m][n][0], sT[m][n][1]), fmaxf(sT[m][n][2], sT[m][n][3]));
      float pmax = fmaxf(fmaxf(mx[0], mx[1]), fmaxf(mx[2], mx[3]));
      pmax = fmaxf(pmax, __shfl_xor(pmax, 16, 64));
      pmax = fmaxf(pmax, __shfl_xor(pmax, 32, 64));
      // T13 defer-max: only rescale when some row grew by > 8 (log2 domain)
      if (!__all(pmax - mrun[m] <= 8.f)) {
        float mnew = fmaxf(mrun[m], pmax);
        float alpha = exp2f(mrun[m] - mnew);   // per-lane scalar (col=q=lm)
#pragma unroll
        for (int n = 0; n < 4; ++n)
#pragma unroll
          for (int j = 0; j < 4; ++j) oaccT[m][n][j] *= alpha;
        lrun[m] *= alpha;
        mrun[m] = mnew;
      }
      int row = m * 16 + lm;
#pragma unroll
      for (int n = 0; n < 4; ++n) {
        half4v p4;
        float pp[4];
#pragma unroll
        for (int j = 0; j < 4; ++j) {
          pp[j] = exp2f(sT[m][n][j] - mrun[m]);  // log2-domain; bounded by 2^8
          p4[j] = (_Float16)pp[j];
        }
        ps[n] = (pp[0] + pp[1]) + (pp[2] + pp[3]);
        int byte = row * 128 + (((n * 32 + lg * 8)) ^ ((row & 7) << 4));
        *(half4v*)(&Plds[byte]) = p4;
      }
      lrun[m] += (ps[0] + ps[1]) + (ps[2] + ps[3]);  // per-lane partial, no shfl
    }
    // read P as fragments (B-operand of transposed PV; bit-identical read)
    half8 pa[2][2];
#pragma unroll
    for (int m = 0; m < 2; ++m)
#pragma unroll
      for (int ks = 0; ks < 2; ++ks) {
        int row = m * 16 + lm;
        int byte = row * 128 + ((ks * 64 + lg * 16) ^ ((row & 7) << 4));
        pa[m][ks] = *(const half8*)(&Plds[byte]);
      }
    __builtin_amdgcn_s_setprio(1);
#pragma unroll
    for (int n = 0; n < 4; ++n)
#pragma unroll
      for (int m = 0; m < 2; ++m) {
        // O^T = V^T * P^T : rows=d (vf), cols=q (pa)
        oaccT[m][n] = __builtin_amdgcn_mfma_f32_16x16x32_f16(vf[n][0], pa[m][0], oaccT[m][n], 0, 0, 0);
        oaccT[m][n] = __builtin_amdgcn_mfma_f32_16x16x32_f16(vf[n][1], pa[m][1], oaccT[m][n], 0, 0, 0);
      }
    __builtin_amdgcn_s_setprio(0);
  }
  // epilogue: reduce lrun partials across the 4 lanes sharing each q-row, normalize,
  // transpose O^T -> O through LDS, coalesced 16B stores
  int b = bh >> 4, h = bh & 15;
#pragma unroll
  for (int m = 0; m < 2; ++m) {
    float lsum = lrun[m];
    lsum += __shfl_xor(lsum, 16, 64);
    lsum += __shfl_xor(lsum, 32, 64);
    float rinv = 1.0f / lsum;
    int row = m * 16 + lm;       // q-local row this lane owns
#pragma unroll
    for (int n = 0; n < 4; ++n) {
      half4v p4;
#pragma unroll
      for (int j = 0; j < 4; ++j) p4[j] = (_Float16)(oaccT[m][n][j] * rinv);
      int byte = row * 128 + ((n * 32 + lg * 8) ^ ((row & 7) << 4));
      *(half4v*)(&Plds[byte]) = p4;
    }
  }
#pragma unroll
  for (int r = 0; r < 4; ++r) {
    int o = r * 1024 + l * 16;
    int row = o >> 7;            // 0..31
    int pb = o & 127;
    int d2 = pb ^ ((row & 7) << 4);  // logical byte-col (d*2)
    half8 v = *(const half8*)&Plds[row * 128 + pb];
    *(half8*)&out[((size_t)(b * 2048 + q0 + row)) * 1024 + h * 64 + (d2 >> 1)] = v;
  }
}

extern "C" void kernel_launch(void* const* d_in, const int* in_sizes, int n_in,
                              void* d_out, int out_size, void* d_ws, size_t ws_size,
                              hipStream_t stream) {
  const float* x = (const float*)d_in[0];
  const int* mask = (const int*)d_in[1];
  const float* Wq = (const float*)d_in[2];
  const float* bq = (const float*)d_in[3];
  const float* Wk = (const float*)d_in[4];
  const float* bk = (const float*)d_in[5];
  const float* Wv = (const float*)d_in[6];
  const float* bv = (const float*)d_in[7];
  const float* Wo = (const float*)d_in[8];
  const float* bo = (const float*)d_in[9];

  char* ws = (char*)d_ws;
  _Float16* xh = (_Float16*)(ws);                       // 16 MB, later reused as attn out
  _Float16* Wqh = (_Float16*)(ws + (16ull << 20));      // 2 MB
  _Float16* Wkh = (_Float16*)(ws + (18ull << 20));      // 2 MB
  _Float16* Wvh = (_Float16*)(ws + (20ull << 20));      // 2 MB
  _Float16* Woh = (_Float16*)(ws + (22ull << 20));      // 2 MB
  _Float16* Vt = (_Float16*)(ws + (24ull << 20));       // 16 MB
  unsigned char* flags = (unsigned char*)(ws + (40ull << 20));  // 512 B
  // Q and K scratch live inside d_out (32 MB fp32), fully overwritten by final GEMM
  _Float16* Qw = (_Float16*)d_out;
  _Float16* Kw = (_Float16*)((char*)d_out + (16ull << 20));
  _Float16* Ah = xh;  // attention output reuses x-f16 region

  const float QSCALE = 0.125f * 1.4426950408889634f;  // 1/sqrt(64) * log2(e)

  cvt_f32_f16<<<8192, 256, 0, stream>>>(x, xh, 2097152);
  cvt_f32_f16<<<1024, 256, 0, stream>>>(Wq, Wqh, 262144);
  cvt_f32_f16<<<1024, 256, 0, stream>>>(Wk, Wkh, 262144);
  cvt_f32_f16<<<1024, 256, 0, stream>>>(Wv, Wvh, 262144);
  cvt_f32_f16<<<1024, 256, 0, stream>>>(Wo, Woh, 262144);
  mask_flags_k<<<dim3(16, 32), 256, 0, stream>>>(mask, flags);
  gemm_k<0><<<dim3(8, 64), 256, 0, stream>>>(xh, Wqh, bq, Qw, QSCALE);
  gemm_k<0><<<dim3(8, 64), 256, 0, stream>>>(xh, Wkh, bk, Kw, 1.0f);
  gemm_k<1><<<dim3(8, 64), 256, 0, stream>>>(xh, Wvh, bv, Vt, 1.0f);
  attn_k<<<dim3(64, 64), 64, 0, stream>>>(Qw, Kw, Vt, flags, mask, Ah);
  gemm_k<2><<<dim3(8, 64), 256, 0, stream>>>(Ah, Woh, bo, d_out, 1.0f);
}

// Round 13
// 363.488 us; speedup vs baseline: 1.6368x; 1.0081x over previous
//
#include <hip/hip_runtime.h>

typedef _Float16 half8 __attribute__((ext_vector_type(8)));
typedef _Float16 half4v __attribute__((ext_vector_type(4)));
typedef __fp16 fp16x2 __attribute__((ext_vector_type(2)));
typedef float f32x4 __attribute__((ext_vector_type(4)));

__device__ __forceinline__ void gld_lds16(const void* g, void* l) {
  __builtin_amdgcn_global_load_lds((const __attribute__((address_space(1))) void*)g,
                                   (__attribute__((address_space(3))) void*)l, 16, 0, 0);
}

// raw v_exp_f32 — exp2f without fast-math lowers to __ocml_exp2_f32 with denormal
// fixup (~8 inst); our args are in [-40, 0] so the raw instruction is exact enough.
__device__ __forceinline__ float fexp2(float x) { return __builtin_amdgcn_exp2f(x); }

// pack four f32 -> 4xf16 via two v_cvt_pkrtz_f16_f32 (bit-cast __fp16x2 -> _Float16x4)
__device__ __forceinline__ half4v pk4(float a, float b, float c, float d) {
  union { fp16x2 p[2]; half4v v; } u;
  u.p[0] = __builtin_amdgcn_cvt_pkrtz(a, b);
  u.p[1] = __builtin_amdgcn_cvt_pkrtz(c, d);
  return u.v;
}

// ---------------- fp32 -> f16 convert (vectorized) ----------------
__global__ void cvt_f32_f16(const float* __restrict__ src, _Float16* __restrict__ dst, int n4) {
  int i = blockIdx.x * 256 + threadIdx.x;
  if (i < n4) {
    float4 v = ((const float4*)src)[i];
    half4v h;
    h.x = (_Float16)v.x; h.y = (_Float16)v.y; h.z = (_Float16)v.z; h.w = (_Float16)v.w;
    ((half4v*)dst)[i] = h;
  }
}

// ---------------- mask tile flags: flag=1 iff no zeros in 128x64 tile ----------------
__global__ void mask_flags_k(const int* __restrict__ mask, unsigned char* __restrict__ flags) {
  int qt = blockIdx.x, kt = blockIdx.y; // 16 x 32
  __shared__ int allv;
  if (threadIdx.x == 0) allv = 1;
  __syncthreads();
  int ok = 1;
  for (int idx = threadIdx.x; idx < 128 * 64; idx += 256) {
    int qr = qt * 128 + (idx >> 6);
    int kc = kt * 64 + (idx & 63);
    ok &= (mask[(size_t)qr * 2048 + kc] != 0);
  }
  if (!ok) atomicAnd(&allv, 0);
  __syncthreads();
  if (threadIdx.x == 0) flags[qt * 32 + kt] = (unsigned char)allv;
}

// ---------------- GEMM: y[M=8192,N=1024] = A[M,1024] @ B[N,1024]^T + bias, * oscale ----------
// LAYOUT 0: f16 heads [b,h,s,d]   LAYOUT 1: f16 V^T [b,h,d,s]   LAYOUT 2: fp32 [row,col]
// XCD-aware remap (T1): linear wg -> xcd = wg&7 owns an 8x8 (m,n) tile block so A-panels
// and B-panels are shared within one XCD's L2 (working set 4MB). Bijective for 512 blocks.
template <int LAYOUT>
__global__ __launch_bounds__(256, 2) void gemm_k(const _Float16* __restrict__ A,
                                                 const _Float16* __restrict__ B,
                                                 const float* __restrict__ bias,
                                                 void* __restrict__ dst, float oscale) {
  __shared__ _Float16 Alds[128][32];
  __shared__ _Float16 Blds[128][32];
  int tid = threadIdx.x, w = tid >> 6, l = tid & 63;
  int lm = l & 15, lg = l >> 4;
  int wm = w >> 1, wn = w & 1;
  int wg = blockIdx.y * 8 + blockIdx.x;  // linear id, x fastest
  int xcd = wg & 7, j = wg >> 3;
  int m0 = (xcd * 8 + (j >> 3)) * 128, n0 = (j & 7) * 128;
  f32x4 acc[4][4] = {};
  for (int k0 = 0; k0 < 1024; k0 += 32) {
#pragma unroll
    for (int c = 0; c < 2; ++c) {
      int o = w * 2048 + c * 1024 + l * 16;  // byte offset within 8KB tile
      int row = o >> 6;
      int kb = (o & 63) >> 1;  // f16 element offset within row
      gld_lds16(A + (size_t)(m0 + row) * 1024 + k0 + kb, (char*)&Alds[0][0] + w * 2048 + c * 1024);
      gld_lds16(B + (size_t)(n0 + row) * 1024 + k0 + kb, (char*)&Blds[0][0] + w * 2048 + c * 1024);
    }
    __syncthreads();
    half8 af[4], bf[4];
#pragma unroll
    for (int m = 0; m < 4; ++m) af[m] = *(const half8*)&Alds[wm * 64 + m * 16 + lm][lg * 8];
#pragma unroll
    for (int n = 0; n < 4; ++n) bf[n] = *(const half8*)&Blds[wn * 64 + n * 16 + lm][lg * 8];
#pragma unroll
    for (int m = 0; m < 4; ++m)
#pragma unroll
      for (int n = 0; n < 4; ++n)
        acc[m][n] = __builtin_amdgcn_mfma_f32_16x16x32_f16(af[m], bf[n], acc[m][n], 0, 0, 0);
    __syncthreads();
  }
  float bs[4];
#pragma unroll
  for (int n = 0; n < 4; ++n) bs[n] = bias[n0 + wn * 64 + n * 16 + lm];
#pragma unroll
  for (int m = 0; m < 4; ++m) {
#pragma unroll
    for (int n = 0; n < 4; ++n) {
      int colg = n0 + wn * 64 + n * 16 + lm;
#pragma unroll
      for (int j2 = 0; j2 < 4; ++j2) {
        int rowg = m0 + wm * 64 + m * 16 + lg * 4 + j2;
        float v = (acc[m][n][j2] + bs[n]) * oscale;
        if constexpr (LAYOUT == 0) {
          int b = rowg >> 11, s = rowg & 2047, h = colg >> 6, d = colg & 63;
          ((_Float16*)dst)[((size_t)(b * 16 + h) * 2048 + s) * 64 + d] = (_Float16)v;
        } else if constexpr (LAYOUT == 1) {
          int b = rowg >> 11, s = rowg & 2047, h = colg >> 6, d = colg & 63;
          ((_Float16*)dst)[((size_t)(b * 16 + h) * 64 + d) * 2048 + s] = (_Float16)v;
        } else {
          ((float*)dst)[(size_t)rowg * 1024 + colg] = v;
        }
      }
    }
  }
}

// ---------------- flash attention ----------------
// ROUND 13 == ROUND 12 with the cvt_pkrtz type fixed (union bit-cast; builtin returns
// __fp16x2). R11 structure unchanged: 1-wave blocks, grid (64,64), natural VGPR~124,
// V-then-K(t+1) ordering, per-lane lrun partials, transposed PV, defer-max.
// VALU diet: raw v_exp_f32 instead of __ocml_exp2_f32 libcall; pkrtz f16 packing.
__global__ __launch_bounds__(64) void attn_k(const _Float16* __restrict__ Q,
                                             const _Float16* __restrict__ K,
                                             const _Float16* __restrict__ Vt,
                                             const unsigned char* __restrict__ flags,
                                             const int* __restrict__ mask,
                                             _Float16* __restrict__ out) {
  __shared__ __align__(16) char Plds[4096];  // 32 rows x 128B, XOR-swizzled
  int bh = blockIdx.x, q32 = blockIdx.y;
  int l = threadIdx.x & 63;
  int lm = l & 15, lg = l >> 4;
  const size_t hb = (size_t)bh * (2048 * 64);
  int q0 = q32 * 32;
  const _Float16* Kb = K + hb;
  const _Float16* Vb = Vt + hb;
  const unsigned char* fl = flags + (q32 >> 2) * 32;

  half8 qf[2][2];
#pragma unroll
  for (int m = 0; m < 2; ++m)
#pragma unroll
    for (int kk = 0; kk < 2; ++kk)
      qf[m][kk] = *(const half8*)&Q[hb + (size_t)(q0 + m * 16 + lm) * 64 + kk * 32 + lg * 8];

  f32x4 oaccT[2][4] = {};           // O^T: col=q=lm (per-lane row), row=d
  float mrun[2] = {-1e30f, -1e30f};
  float lrun[2] = {0.f, 0.f};       // per-lane PARTIAL row-sums (reduced in epilogue)

  // K fragments for tile 0
  half8 kf[4][2];
#pragma unroll
  for (int n = 0; n < 4; ++n)
#pragma unroll
    for (int kk = 0; kk < 2; ++kk)
      kf[n][kk] = *(const half8*)&Kb[(size_t)(n * 16 + lm) * 64 + kk * 32 + lg * 8];

  for (int t = 0; t < 32; ++t) {
    int flg = fl[t];
    f32x4 sT[2][4];
    f32x4 z = {0.f, 0.f, 0.f, 0.f};
    __builtin_amdgcn_s_setprio(1);
#pragma unroll
    for (int m = 0; m < 2; ++m)
#pragma unroll
      for (int n = 0; n < 4; ++n) {
        sT[m][n] = __builtin_amdgcn_mfma_f32_16x16x32_f16(kf[n][0], qf[m][0], z, 0, 0, 0);
        sT[m][n] = __builtin_amdgcn_mfma_f32_16x16x32_f16(kf[n][1], qf[m][1], sT[m][n], 0, 0, 0);
      }
    __builtin_amdgcn_s_setprio(0);
    // V for THIS tile: latency hides under softmax; oldest in vmcnt queue.
    half8 vf[4][2];
#pragma unroll
    for (int n = 0; n < 4; ++n)
#pragma unroll
      for (int kk = 0; kk < 2; ++kk)
        vf[n][kk] = *(const half8*)&Vb[(size_t)(n * 16 + lm) * 2048 + t * 64 + kk * 32 + lg * 8];
    // K for NEXT tile, issued AFTER V: PV's wait for V does not drain these.
    if (t < 31) {
#pragma unroll
      for (int n = 0; n < 4; ++n)
#pragma unroll
        for (int kk = 0; kk < 2; ++kk)
          kf[n][kk] = *(const half8*)&Kb[(size_t)((t + 1) * 64 + n * 16 + lm) * 64 + kk * 32 + lg * 8];
    }
    if (!flg) {  // slow path: per-element mask (not taken for all-ones mask)
#pragma unroll
      for (int m = 0; m < 2; ++m)
#pragma unroll
        for (int n = 0; n < 4; ++n)
#pragma unroll
          for (int j = 0; j < 4; ++j) {
            int qr = q0 + m * 16 + lm;
            int kc = t * 64 + n * 16 + lg * 4 + j;
            if (mask[(size_t)qr * 2048 + kc] == 0) sT[m][n][j] = -1e30f;
          }
    }
#pragma unroll
    for (int m = 0; m < 2; ++m) {
      float mx[4], ps[4];
#pragma unroll
      for (int n = 0; n < 4; ++n)
        mx[n] = fmaxf(fmaxf(sT[m][n][0], sT[m][n][1]), fmaxf(sT[m][n][2], sT[m][n][3]));
      float pmax = fmaxf(fmaxf(mx[0], mx[1]), fmaxf(mx[2], mx[3]));
      pmax = fmaxf(pmax, __shfl_xor(pmax, 16, 64));
      pmax = fmaxf(pmax, __shfl_xor(pmax, 32, 64));
      // T13 defer-max: only rescale when some row grew by > 8 (log2 domain)
      if (!__all(pmax - mrun[m] <= 8.f)) {
        float mnew = fmaxf(mrun[m], pmax);
        float alpha = fexp2(mrun[m] - mnew);   // per-lane scalar (col=q=lm)
#pragma unroll
        for (int n = 0; n < 4; ++n)
#pragma unroll
          for (int j = 0; j < 4; ++j) oaccT[m][n][j] *= alpha;
        lrun[m] *= alpha;
        mrun[m] = mnew;
      }
      int row = m * 16 + lm;
#pragma unroll
      for (int n = 0; n < 4; ++n) {
        float pp0 = fexp2(sT[m][n][0] - mrun[m]);
        float pp1 = fexp2(sT[m][n][1] - mrun[m]);
        float pp2 = fexp2(sT[m][n][2] - mrun[m]);
        float pp3 = fexp2(sT[m][n][3] - mrun[m]);
        ps[n] = (pp0 + pp1) + (pp2 + pp3);
        int byte = row * 128 + (((n * 32 + lg * 8)) ^ ((row & 7) << 4));
        *(half4v*)(&Plds[byte]) = pk4(pp0, pp1, pp2, pp3);
      }
      lrun[m] += (ps[0] + ps[1]) + (ps[2] + ps[3]);  // per-lane partial, no shfl
    }
    // read P as fragments (B-operand of transposed PV; bit-identical read)
    half8 pa[2][2];
#pragma unroll
    for (int m = 0; m < 2; ++m)
#pragma unroll
      for (int ks = 0; ks < 2; ++ks) {
        int row = m * 16 + lm;
        int byte = row * 128 + ((ks * 64 + lg * 16) ^ ((row & 7) << 4));
        pa[m][ks] = *(const half8*)(&Plds[byte]);
      }
    __builtin_amdgcn_s_setprio(1);
#pragma unroll
    for (int n = 0; n < 4; ++n)
#pragma unroll
      for (int m = 0; m < 2; ++m) {
        // O^T = V^T * P^T : rows=d (vf), cols=q (pa)
        oaccT[m][n] = __builtin_amdgcn_mfma_f32_16x16x32_f16(vf[n][0], pa[m][0], oaccT[m][n], 0, 0, 0);
        oaccT[m][n] = __builtin_amdgcn_mfma_f32_16x16x32_f16(vf[n][1], pa[m][1], oaccT[m][n], 0, 0, 0);
      }
    __builtin_amdgcn_s_setprio(0);
  }
  // epilogue: reduce lrun partials across the 4 lanes sharing each q-row, normalize,
  // transpose O^T -> O through LDS, coalesced 16B stores
  int b = bh >> 4, h = bh & 15;
#pragma unroll
  for (int m = 0; m < 2; ++m) {
    float lsum = lrun[m];
    lsum += __shfl_xor(lsum, 16, 64);
    lsum += __shfl_xor(lsum, 32, 64);
    float rinv = 1.0f / lsum;
    int row = m * 16 + lm;       // q-local row this lane owns
#pragma unroll
    for (int n = 0; n < 4; ++n) {
      int byte = row * 128 + ((n * 32 + lg * 8) ^ ((row & 7) << 4));
      *(half4v*)(&Plds[byte]) = pk4(oaccT[m][n][0] * rinv, oaccT[m][n][1] * rinv,
                                    oaccT[m][n][2] * rinv, oaccT[m][n][3] * rinv);
    }
  }
#pragma unroll
  for (int r = 0; r < 4; ++r) {
    int o = r * 1024 + l * 16;
    int row = o >> 7;            // 0..31
    int pb = o & 127;
    int d2 = pb ^ ((row & 7) << 4);  // logical byte-col (d*2)
    half8 v = *(const half8*)&Plds[row * 128 + pb];
    *(half8*)&out[((size_t)(b * 2048 + q0 + row)) * 1024 + h * 64 + (d2 >> 1)] = v;
  }
}

extern "C" void kernel_launch(void* const* d_in, const int* in_sizes, int n_in,
                              void* d_out, int out_size, void* d_ws, size_t ws_size,
                              hipStream_t stream) {
  const float* x = (const float*)d_in[0];
  const int* mask = (const int*)d_in[1];
  const float* Wq = (const float*)d_in[2];
  const float* bq = (const float*)d_in[3];
  const float* Wk = (const float*)d_in[4];
  const float* bk = (const float*)d_in[5];
  const float* Wv = (const float*)d_in[6];
  const float* bv = (const float*)d_in[7];
  const float* Wo = (const float*)d_in[8];
  const float* bo = (const float*)d_in[9];

  char* ws = (char*)d_ws;
  _Float16* xh = (_Float16*)(ws);                       // 16 MB, later reused as attn out
  _Float16* Wqh = (_Float16*)(ws + (16ull << 20));      // 2 MB
  _Float16* Wkh = (_Float16*)(ws + (18ull << 20));      // 2 MB
  _Float16* Wvh = (_Float16*)(ws + (20ull << 20));      // 2 MB
  _Float16* Woh = (_Float16*)(ws + (22ull << 20));      // 2 MB
  _Float16* Vt = (_Float16*)(ws + (24ull << 20));       // 16 MB
  unsigned char* flags = (unsigned char*)(ws + (40ull << 20));  // 512 B
  // Q and K scratch live inside d_out (32 MB fp32), fully overwritten by final GEMM
  _Float16* Qw = (_Float16*)d_out;
  _Float16* Kw = (_Float16*)((char*)d_out + (16ull << 20));
  _Float16* Ah = xh;  // attention output reuses x-f16 region

  const float QSCALE = 0.125f * 1.4426950408889634f;  // 1/sqrt(64) * log2(e)

  cvt_f32_f16<<<8192, 256, 0, stream>>>(x, xh, 2097152);
  cvt_f32_f16<<<1024, 256, 0, stream>>>(Wq, Wqh, 262144);
  cvt_f32_f16<<<1024, 256, 0, stream>>>(Wk, Wkh, 262144);
  cvt_f32_f16<<<1024, 256, 0, stream>>>(Wv, Wvh, 262144);
  cvt_f32_f16<<<1024, 256, 0, stream>>>(Wo, Woh, 262144);
  mask_flags_k<<<dim3(16, 32), 256, 0, stream>>>(mask, flags);
  gemm_k<0><<<dim3(8, 64), 256, 0, stream>>>(xh, Wqh, bq, Qw, QSCALE);
  gemm_k<0><<<dim3(8, 64), 256, 0, stream>>>(xh, Wkh, bk, Kw, 1.0f);
  gemm_k<1><<<dim3(8, 64), 256, 0, stream>>>(xh, Wvh, bv, Vt, 1.0f);
  attn_k<<<dim3(64, 64), 64, 0, stream>>>(Qw, Kw, Vt, flags, mask, Ah);
  gemm_k<2><<<dim3(8, 64), 256, 0, stream>>>(Ah, Woh, bo, d_out, 1.0f);
}